// Round 8
// baseline (585.634 us; speedup 1.0000x reference)
//
#include <hip/hip_runtime.h>
#include <math.h>

// Problem constants (fixed by the reference)
#define G    120     // B*T frames
#define Nn   2000    // nodes per frame
#define Ee   32000   // edges per frame
#define Tt   30
#define Bb   4
#define Fg   128     // GRU hidden
#define QCAP 9216    // CSR capacity per (frame,quadrant); expected 8000, sigma 78
#define ESL  36      // sorted-ELL slots/node: <=32 entries (self+31) + <=4 even-pads

typedef unsigned short ushort8 __attribute__((ext_vector_type(8)));

static __device__ __forceinline__ unsigned short f2bf(float f) {
    unsigned u = __float_as_uint(f);
    u += 0x7fffu + ((u >> 16) & 1u);          // round-to-nearest-even
    return (unsigned short)(u >> 16);
}

// ---- K1: fused CSR build: histogram + scan + fill in LDS, coalesced write-out.
__global__ void __launch_bounds__(1024, 1)
k_csr(const int* __restrict__ ei, float* __restrict__ dis,
      int* __restrict__ startA, int* __restrict__ cntA,
      int* __restrict__ csr, float* __restrict__ emb) {
    __shared__ int hist[500];      // histogram, then cursor
    __shared__ int ws[512];        // scan workspace
    __shared__ int csr_l[QCAP];
    int gq = blockIdx.x;
    int g = gq >> 2, q = gq & 3;
    int lo = q * 500, hi = lo + 500;
    int tid = threadIdx.x;
    if (tid < 500) hist[tid] = 0;
    if (q == 0 && tid < 64) emb[g * 64 + tid] = 0.f;
    __syncthreads();
    const int* srcp = ei + (size_t)g * 2 * Ee;
    const int* dstp = srcp + Ee;
    for (int i = tid; i < Ee / 4; i += 1024) {
        int4 d = reinterpret_cast<const int4*>(dstp)[i];
        if (d.x >= lo && d.x < hi) atomicAdd(&hist[d.x - lo], 1);
        if (d.y >= lo && d.y < hi) atomicAdd(&hist[d.y - lo], 1);
        if (d.z >= lo && d.z < hi) atomicAdd(&hist[d.z - lo], 1);
        if (d.w >= lo && d.w < hi) atomicAdd(&hist[d.w - lo], 1);
    }
    __syncthreads();
    if (tid < 512) ws[tid] = (tid < 500) ? hist[tid] : 0;
    __syncthreads();
    for (int off = 1; off < 512; off <<= 1) {
        int v = 0;
        if (tid < 512 && tid >= off) v = ws[tid - off];
        __syncthreads();
        if (tid < 512) ws[tid] += v;
        __syncthreads();
    }
    if (tid < 500) {
        int cnt = hist[tid];
        int ex = ws[tid] - cnt;                    // exclusive prefix
        int n = lo + tid;
        startA[(size_t)g * Nn + n] = gq * QCAP + ex;
        cntA[(size_t)g * Nn + n]   = cnt;
        dis[(size_t)g * Nn + n]    = rsqrtf((float)cnt + 1.0f);
        hist[tid] = ex;                            // reuse as cursor
    }
    __syncthreads();
    for (int i = tid; i < Ee / 4; i += 1024) {
        int4 d = reinterpret_cast<const int4*>(dstp)[i];
        int4 s = reinterpret_cast<const int4*>(srcp)[i];
        if (d.x >= lo && d.x < hi) { int p = atomicAdd(&hist[d.x - lo], 1); if (p < QCAP) csr_l[p] = s.x; }
        if (d.y >= lo && d.y < hi) { int p = atomicAdd(&hist[d.y - lo], 1); if (p < QCAP) csr_l[p] = s.y; }
        if (d.z >= lo && d.z < hi) { int p = atomicAdd(&hist[d.z - lo], 1); if (p < QCAP) csr_l[p] = s.z; }
        if (d.w >= lo && d.w < hi) { int p = atomicAdd(&hist[d.w - lo], 1); if (p < QCAP) csr_l[p] = s.w; }
    }
    __syncthreads();
    int total = ws[511];
    int* cg = csr + (size_t)gq * QCAP;
    for (int i = tid; i < total; i += 1024) cg[i] = csr_l[i];
}

// ---- K2: quarter-sorted even-padded ELL, built in LDS, coalesced write-out.
// Per node: runs for src-quarter 0..3 (local src idx, folded weight), each run
// even-length (pads = (0, w=0)); self-loop included; counts packed in cnt4p.
// One block per (frame, 128-node group); thread = node.
__global__ void __launch_bounds__(256)
k_ell2(const float* __restrict__ dis, const int* __restrict__ startA,
       const int* __restrict__ cntA, const int* __restrict__ csr,
       int2* __restrict__ ell, int* __restrict__ cnt4p) {
    __shared__ int2 lbuf[128 * ESL];          // 36.9 KB
    int g = blockIdx.y;
    int bx = blockIdx.x;                      // 0..15
    int tid = threadIdx.x;
    int n = bx * 128 + tid;
    int nvalid = min(128, Nn - bx * 128);
    if (tid < 128 && n < Nn) {
        size_t gn = (size_t)g * Nn + n;
        int cnt = cntA[gn], start = startA[gn];
        int m = min(cnt, 31);
        float dn = dis[gn];
        const float* dsg = dis + (size_t)g * Nn;
        int c0 = 0, c1 = 0, c2 = 0, c3 = 0;
        for (int j = 0; j < m; ++j) {
            int s = csr[start + j];
            if (s < 500) c0++; else if (s < 1000) c1++; else if (s < 1500) c2++; else c3++;
        }
        int qn = (n >= 1000) ? ((n >= 1500) ? 3 : 2) : ((n >= 500) ? 1 : 0);
        if (qn == 0) c0++; else if (qn == 1) c1++; else if (qn == 2) c2++; else c3++;
        int p0 = c0 + (c0 & 1), p1 = c1 + (c1 & 1), p2 = c2 + (c2 & 1), p3 = c3 + (c3 & 1);
        cnt4p[gn] = p0 | (p1 << 8) | (p2 << 16) | (p3 << 24);
        int u0 = 0, u1 = p0, u2 = p0 + p1, u3 = p0 + p1 + p2;
        int2* lb = lbuf + tid * ESL;
        // self-loop
        {
            int2 v = make_int2(n - qn * 500, __float_as_int(dn * dn));
            if (qn == 0) lb[u0++] = v; else if (qn == 1) lb[u1++] = v;
            else if (qn == 2) lb[u2++] = v; else lb[u3++] = v;
        }
        for (int j = 0; j < m; ++j) {
            int s = csr[start + j];
            int2 v = make_int2(0, __float_as_int(dsg[s] * dn));
            if (s < 500)       { v.x = s;        lb[u0++] = v; }
            else if (s < 1000) { v.x = s - 500;  lb[u1++] = v; }
            else if (s < 1500) { v.x = s - 1000; lb[u2++] = v; }
            else               { v.x = s - 1500; lb[u3++] = v; }
        }
        int2 pad = make_int2(0, 0);
        if (c0 & 1) lb[u0] = pad;
        if (c1 & 1) lb[u1] = pad;
        if (c2 & 1) lb[u2] = pad;
        if (c3 & 1) lb[u3] = pad;
    }
    __syncthreads();
    // coalesced write-out (nvalid*ESL int2 = nvalid*18 int4)
    int nint4 = nvalid * 18;
    const int4* lsrc = reinterpret_cast<const int4*>(lbuf);
    int4* gdst = reinterpret_cast<int4*>(ell + ((size_t)g * Nn + bx * 128) * ESL);
    for (int i = tid; i < nint4; i += 256) gdst[i] = lsrc[i];
}

// ---- K3: fused per-node pipeline: aggX = sorted-ELL-agg(x) -> h1 -> t2 (bf16).
// 32 nodes/block, XCD-pinned.
__global__ void __launch_bounds__(256)
k_mmf(const float* __restrict__ x, const int2* __restrict__ ell,
      const int* __restrict__ cnt4p, const int* __restrict__ startA,
      const int* __restrict__ cntA, const int* __restrict__ csr,
      const float* __restrict__ dis,
      const float* __restrict__ W1, const float* __restrict__ b1,
      const float* __restrict__ W2, unsigned short* __restrict__ t2b) {
    __shared__ float Ws1[512];
    __shared__ float bs[64];
    __shared__ float xs[256];          // aggX tile: 32 nodes x 8 features
    __shared__ float W2s[4096];
    __shared__ float h1s[32 * 65];
    int i = blockIdx.x;            // 0..7559; round-robin over 8 XCDs
    int xcd = i & 7;
    int j = i >> 3;                // 0..944
    int f15 = j / 63;              // 0..14
    int bx = j % 63;
    int g = xcd * 15 + f15;
    int tid = threadIdx.x;
    Ws1[tid]       = W1[tid];
    Ws1[tid + 256] = W1[tid + 256];
    if (tid < 64) bs[tid] = b1[tid];
#pragma unroll
    for (int k2 = 0; k2 < 16; ++k2) W2s[k2 * 256 + tid] = W2[k2 * 256 + tid];
    // phase 0: sorted-ELL aggregation of raw x (8-dim) into xs
    {
        int r0 = tid >> 3, f = tid & 7;       // node-in-block, feature
        int n = bx * 32 + r0;
        float v = 0.f;
        if (n < Nn) {
            size_t gn = (size_t)g * Nn + n;
            const float* xb = x + (size_t)g * Nn * 8;
            int c4 = cnt4p[gn];
            float acc = 0.f, acc2 = 0.f;
            int eoff = 0;
#pragma unroll
            for (int q = 0; q < 4; ++q) {
                int cq = (c4 >> (8 * q)) & 255;
                const int4* ep = reinterpret_cast<const int4*>(ell + gn * ESL + eoff);
                int np = cq >> 1;
                for (int e = 0; e < np; ++e) {
                    int4 p = ep[e];
                    acc  += xb[(size_t)(p.x + q * 500) * 8 + f] * __int_as_float(p.y);
                    acc2 += xb[(size_t)(p.z + q * 500) * 8 + f] * __int_as_float(p.w);
                }
                eoff += cq;
            }
            int cnt = cntA[gn];
            if (cnt > 31) {                    // rare overflow (deg > 31)
                float dnl = dis[gn];
                int o0 = startA[gn];
                const float* dsg = dis + (size_t)g * Nn;
                for (int e = 31; e < cnt; ++e) {
                    int s = csr[o0 + e];
                    acc += xb[(size_t)s * 8 + f] * (dsg[s] * dnl);
                }
            }
            v = acc + acc2;
        }
        xs[tid] = v;                           // tid == r0*8+f
    }
    __syncthreads();
    // phase 1: h1 = relu(aggX@W1 + b1) into LDS
    int f = tid & 63, rr = tid >> 6;
#pragma unroll
    for (int ii = 0; ii < 8; ++ii) {
        int r = rr + 4 * ii;
        float acc = bs[f];
#pragma unroll
        for (int k = 0; k < 8; ++k) acc += xs[r * 8 + k] * Ws1[k * 64 + f];
        h1s[r * 65 + f] = fmaxf(acc, 0.f);
    }
    __syncthreads();
    // phase 2: t2 = h1 @ W2 (bf16 out), each thread: 1 node x 8 features
    int r2 = tid >> 3, fg = tid & 7;
    int n = bx * 32 + r2;
    if (n < Nn) {
        float4 a0 = {0.f, 0.f, 0.f, 0.f}, a1 = {0.f, 0.f, 0.f, 0.f};
        const float4* W24 = reinterpret_cast<const float4*>(W2s);
#pragma unroll 8
        for (int k = 0; k < 64; ++k) {
            float xv = h1s[r2 * 65 + k];
            float4 w0 = W24[k * 16 + fg * 2];
            float4 w1 = W24[k * 16 + fg * 2 + 1];
            a0.x += xv * w0.x; a0.y += xv * w0.y; a0.z += xv * w0.z; a0.w += xv * w0.w;
            a1.x += xv * w1.x; a1.y += xv * w1.y; a1.z += xv * w1.z; a1.w += xv * w1.w;
        }
        ushort8 ov;
        ov[0] = f2bf(a0.x); ov[1] = f2bf(a0.y); ov[2] = f2bf(a0.z); ov[3] = f2bf(a0.w);
        ov[4] = f2bf(a1.x); ov[5] = f2bf(a1.y); ov[6] = f2bf(a1.z); ov[7] = f2bf(a1.w);
        *reinterpret_cast<ushort8*>(t2b + ((size_t)g * Nn + n) * 64 + fg * 8) = ov;
    }
}

// ---- K4: h2 = relu(agg(t2)+b2) + mean-pool, with t2 staged through LDS.
// Block = (frame, 250-node slice), 1024 thr = 16 waves, wave = 16 nodes.
// 4 passes; pass q stages t2 quarter q (500x64 bf16 = 62.5 KB) in LDS; all
// row gathers are conflict-free ds_read_b32 (2 entries/wave-instr, 2 feat/lane).
__global__ void __launch_bounds__(1024)
k_aggL(const unsigned short* __restrict__ t2b, const int2* __restrict__ ell,
       const int* __restrict__ cnt4p, const int* __restrict__ startA,
       const int* __restrict__ cntA, const int* __restrict__ csr,
       const float* __restrict__ dis, const float* __restrict__ bias,
       float* __restrict__ emb) {
    __shared__ ushort stage[500 * 64];        // 64000 B; reused for pool reduce
    int i = blockIdx.x;                       // 0..959
    int xcd = i & 7;
    int j = i >> 3;                           // 0..119
    int g = xcd * 15 + (j >> 3);
    int slice = j & 7;
    int tid = threadIdx.x;
    int w = tid >> 6;                         // wave 0..15
    int L = tid & 63;
    int Lh = L & 31;
    bool hi = (L >= 32);
    float accLo[16], accHi[16];
#pragma unroll
    for (int k = 0; k < 16; ++k) { accLo[k] = 0.f; accHi[k] = 0.f; }
    const unsigned* st32 = reinterpret_cast<const unsigned*>(stage);
#pragma unroll
    for (int q = 0; q < 4; ++q) {
        // stage quarter q of frame g: 8000 ushort8
        {
            const ushort8* src = reinterpret_cast<const ushort8*>(
                t2b + ((size_t)g * Nn + q * 500) * 64);
            ushort8* dst = reinterpret_cast<ushort8*>(stage);
            for (int it = tid; it < 8000; it += 1024) dst[it] = src[it];
        }
        __syncthreads();
#pragma unroll
        for (int iN = 0; iN < 16; ++iN) {
            int idx = w * 16 + iN;
            bool valid = idx < 250;
            size_t gn = (size_t)g * Nn + slice * 250 + idx;
            int c4 = valid ? cnt4p[gn] : 0;
            int eoff = 0;
#pragma unroll
            for (int qq = 0; qq < 4; ++qq) if (qq < q) eoff += (c4 >> (8 * qq)) & 255;
            int np = ((c4 >> (8 * q)) & 255) >> 1;
            const int4* ep = reinterpret_cast<const int4*>(ell + gn * ESL + eoff);
            for (int e = 0; e < np; ++e) {
                int4 p = ep[e];
                int sl = hi ? p.z : p.x;
                float wt = __int_as_float(hi ? p.w : p.y);
                unsigned u = st32[sl * 32 + Lh];
                accLo[iN] += __uint_as_float(u << 16) * wt;
                accHi[iN] += __uint_as_float(u & 0xffff0000u) * wt;
            }
        }
        __syncthreads();
    }
    // rare overflow tail (deg > 31): gather from global t2
    const unsigned* t2u = reinterpret_cast<const unsigned*>(t2b);
#pragma unroll
    for (int iN = 0; iN < 16; ++iN) {
        int idx = w * 16 + iN;
        if (idx < 250) {
            size_t gn = (size_t)g * Nn + slice * 250 + idx;
            int cnt = cntA[gn];
            if (cnt > 31) {
                float dn = dis[gn];
                int o0 = startA[gn];
                const float* dsg = dis + (size_t)g * Nn;
                for (int e = 31; e < cnt; ++e) {
                    int s = csr[o0 + e];
                    float wt = hi ? 0.f : (dsg[s] * dn);
                    unsigned u = t2u[((size_t)g * Nn + s) * 32 + Lh];
                    accLo[iN] += __uint_as_float(u << 16) * wt;
                    accHi[iN] += __uint_as_float(u & 0xffff0000u) * wt;
                }
            }
        }
    }
    // combine halves, bias+relu, pool over the wave's nodes
    float b0 = bias[2 * Lh], b1v = bias[2 * Lh + 1];
    float poolLo = 0.f, poolHi = 0.f;
#pragma unroll
    for (int iN = 0; iN < 16; ++iN) {
        float lo = accLo[iN] + __shfl_down(accLo[iN], 32);
        float hj = accHi[iN] + __shfl_down(accHi[iN], 32);
        if (w * 16 + iN < 250) {
            poolLo += fmaxf(lo + b0, 0.f);
            poolHi += fmaxf(hj + b1v, 0.f);
        }
    }
    __syncthreads();                           // stage free -> reuse as reduce buf
    float* red = reinterpret_cast<float*>(stage);
    if (!hi) {
        red[w * 64 + 2 * Lh]     = poolLo;
        red[w * 64 + 2 * Lh + 1] = poolHi;
    }
    __syncthreads();
    if (tid < 64) {
        float s = 0.f;
#pragma unroll
        for (int k = 0; k < 16; ++k) s += red[k * 64 + tid];
        atomicAdd(&emb[g * 64 + tid], s * (1.0f / Nn));
    }
}

// ---- K5: gi[g][384] = emb[g] @ W_ih^T + b_ih (parallel over frames)
__global__ void k_gi(const float* __restrict__ emb, const float* __restrict__ W_ih,
                     const float* __restrict__ b_ih, float* __restrict__ gi) {
    __shared__ float xs[64];
    int g = blockIdx.x;          // g = b*Tt + t
    int j = threadIdx.x;         // 0..383
    if (j < 64) xs[j] = emb[g * 64 + j];
    __syncthreads();
    float a0 = 0.f, a1 = 0.f, a2 = 0.f, a3 = 0.f;
    const float* wr = W_ih + j * 64;
#pragma unroll
    for (int k = 0; k < 16; ++k) {
        a0 += wr[4 * k + 0] * xs[4 * k + 0];
        a1 += wr[4 * k + 1] * xs[4 * k + 1];
        a2 += wr[4 * k + 2] * xs[4 * k + 2];
        a3 += wr[4 * k + 3] * xs[4 * k + 3];
    }
    gi[(size_t)g * 384 + j] = b_ih[j] + ((a0 + a1) + (a2 + a3));
}

// ---- K6: sequential GRU over T, one block per batch, W_hh in regs + final FC
__global__ void __launch_bounds__(768, 1)
k_gru_seq(const float* __restrict__ gi, const float* __restrict__ W_hh,
          const float* __restrict__ b_hh, const float* __restrict__ fc_w,
          const float* __restrict__ fc_b, float* __restrict__ out) {
    __shared__ float h[Fg];
    __shared__ float part[768];
    int b = blockIdx.x;                  // batch
    int tid = threadIdx.x;               // 0..767
    int row = tid >> 1;                  // gate-row 0..383
    int half = tid & 1;                  // which 64-slice of k
    float w[64];
    const float* wr = W_hh + (size_t)row * Fg + half * 64;
#pragma unroll
    for (int i = 0; i < 64; ++i) w[i] = wr[i];
    if (tid < Fg) h[tid] = 0.f;
    __syncthreads();
    for (int t = 0; t < Tt; ++t) {
        const float* hh = &h[half * 64];
        float a0 = 0.f, a1 = 0.f, a2 = 0.f, a3 = 0.f;
#pragma unroll
        for (int i = 0; i < 16; ++i) {
            a0 += w[4 * i + 0] * hh[4 * i + 0];
            a1 += w[4 * i + 1] * hh[4 * i + 1];
            a2 += w[4 * i + 2] * hh[4 * i + 2];
            a3 += w[4 * i + 3] * hh[4 * i + 3];
        }
        part[tid] = (a0 + a1) + (a2 + a3);
        __syncthreads();
        if (tid < Fg) {
            int j = tid;
            const float* gib = gi + ((size_t)b * Tt + t) * 384;
            float hr = b_hh[j]       + part[2 * j]           + part[2 * j + 1];
            float hz = b_hh[128 + j] + part[2 * (128 + j)]   + part[2 * (128 + j) + 1];
            float hn = b_hh[256 + j] + part[2 * (256 + j)]   + part[2 * (256 + j) + 1];
            float r  = 1.f / (1.f + expf(-(gib[j] + hr)));
            float z  = 1.f / (1.f + expf(-(gib[128 + j] + hz)));
            float nn = tanhf(gib[256 + j] + r * hn);
            h[j] = (1.f - z) * nn + z * h[j];
        }
        __syncthreads();
    }
    if (tid < 2) {
        float acc = fc_b[tid];
        for (int k = 0; k < Fg; ++k) acc += fc_w[tid * Fg + k] * h[k];
        out[b * 2 + tid] = acc;
    }
}

// ----------------------------------------------------------------- launcher
extern "C" void kernel_launch(void* const* d_in, const int* in_sizes, int n_in,
                              void* d_out, int out_size, void* d_ws, size_t ws_size,
                              hipStream_t stream) {
    const float* x     = (const float*)d_in[0];
    const int*   ei    = (const int*)  d_in[1];
    const float* W1    = (const float*)d_in[2];
    const float* b1    = (const float*)d_in[3];
    const float* W2    = (const float*)d_in[4];
    const float* b2    = (const float*)d_in[5];
    const float* W_ih  = (const float*)d_in[6];
    const float* W_hh  = (const float*)d_in[7];
    const float* b_ih  = (const float*)d_in[8];
    const float* b_hh  = (const float*)d_in[9];
    const float* fc_w  = (const float*)d_in[10];
    const float* fc_b  = (const float*)d_in[11];
    float* out = (float*)d_out;

    char* ws = (char*)d_ws;
    size_t off = 0;
    auto alloc = [&](size_t bytes) -> void* {
        void* p = ws + off;
        off = (off + bytes + 255) & ~(size_t)255;
        return p;
    };
    float* dis     = (float*)alloc((size_t)G * Nn * 4);
    int*   startA  = (int*)  alloc((size_t)G * Nn * 4);
    int*   cntA    = (int*)  alloc((size_t)G * Nn * 4);
    int*   cnt4p   = (int*)  alloc((size_t)G * Nn * 4);
    int*   csr     = (int*)  alloc((size_t)G * 4 * QCAP * 4);
    int2*  ell     = (int2*) alloc((size_t)G * Nn * ESL * 8);
    unsigned short* t2b = (unsigned short*)alloc((size_t)G * Nn * 64 * 2);
    float* emb     = (float*)alloc((size_t)G * 64 * 4);
    float* gi      = (float*)alloc((size_t)G * 384 * 4);
    (void)ws_size; (void)in_sizes; (void)n_in; (void)out_size;

    hipLaunchKernelGGL(k_csr,    dim3(G * 4), dim3(1024), 0, stream, ei, dis, startA, cntA, csr, emb);
    hipLaunchKernelGGL(k_ell2,   dim3(16, G), dim3(256), 0, stream, dis, startA, cntA, csr, ell, cnt4p);
    hipLaunchKernelGGL(k_mmf,    dim3(7560), dim3(256), 0, stream, x, ell, cnt4p, startA, cntA, csr, dis, W1, b1, W2, t2b);
    hipLaunchKernelGGL(k_aggL,   dim3(960), dim3(1024), 0, stream, t2b, ell, cnt4p, startA, cntA, csr, dis, b2, emb);
    hipLaunchKernelGGL(k_gi,     dim3(G), dim3(384), 0, stream, emb, W_ih, b_ih, gi);
    hipLaunchKernelGGL(k_gru_seq, dim3(Bb), dim3(768), 0, stream, gi, W_hh, b_hh, fc_w, fc_b, out);
}

// Round 9
// 541.332 us; speedup vs baseline: 1.0818x; 1.0818x over previous
//
#include <hip/hip_runtime.h>
#include <math.h>

// Problem constants (fixed by the reference)
#define G    120     // B*T frames
#define Nn   2000    // nodes per frame
#define Ee   32000   // edges per frame
#define Tt   30
#define Bb   4
#define Fg   128     // GRU hidden
#define QCAP 9216    // CSR capacity per (frame,quadrant); expected 8000, sigma 78
#define SLOT 32      // packed-ELL slots/node (uint each): slot0=self, 1..31 edges, pad w=0

static __device__ __forceinline__ unsigned short f2bf(float f) {
    unsigned u = __float_as_uint(f);
    u += 0x7fffu + ((u >> 16) & 1u);          // round-to-nearest-even
    return (unsigned short)(u >> 16);
}

// ---------------- fp8 e4m3 encode/decode: HW builtins if available, SW fallback.
// NOTE: encode and decode use the SAME hardware interpretation, so round-trip is
// self-consistent regardless of ocp-vs-fnuz naming; values here are ~0.07 scale.
#if defined(__has_builtin)
#if __has_builtin(__builtin_amdgcn_cvt_f32_fp8) && __has_builtin(__builtin_amdgcn_cvt_pk_fp8_f32)
#define HW_FP8 1
#endif
#endif

static __device__ __forceinline__ unsigned fp8_enc_sw(float x) {
    unsigned s = (__float_as_uint(x) >> 24) & 0x80u;
    float ax = fminf(fabsf(x), 448.f);
    unsigned em;
    if (ax < 0.015625f) {                        // < 2^-6 -> denormal
        em = (unsigned)__float2int_rn(ax * 512.f);           // 0..8 (8 = carry to normal)
    } else {
        int e = (int)(__float_as_uint(ax) >> 23) - 127;      // floor(log2 ax)
        float r = ax * __uint_as_float((unsigned)((130 - e) << 23));  // ax*2^(3-e) in [8,16]
        int q = __float2int_rn(r);                           // 8..16 (16 = mantissa carry)
        em = (unsigned)(((e + 7) << 3) + (q - 8));
        em = min(em, 126u);
    }
    return s | em;
}
static __device__ __forceinline__ float fp8_dec_sw(unsigned b) {
    unsigned em = b & 0x7fu;
    float mag;
    if (em < 8u) mag = (float)em * 0.001953125f;             // denormal: m * 2^-9
    else mag = __uint_as_float((((em >> 3) + 120u) << 23) | ((em & 7u) << 20));
    return (b & 0x80u) ? -mag : mag;
}

static __device__ __forceinline__ unsigned fp8_pack4(float a, float b, float c, float d) {
#ifdef HW_FP8
    int w = __builtin_amdgcn_cvt_pk_fp8_f32(a, b, 0, false);
    w = __builtin_amdgcn_cvt_pk_fp8_f32(c, d, w, true);
    return (unsigned)w;
#else
    return fp8_enc_sw(a) | (fp8_enc_sw(b) << 8) | (fp8_enc_sw(c) << 16) | (fp8_enc_sw(d) << 24);
#endif
}
static __device__ __forceinline__ float fp8_dec(unsigned byte_in_low) {
#ifdef HW_FP8
    return __builtin_amdgcn_cvt_f32_fp8((int)byte_in_low, 0);
#else
    return fp8_dec_sw(byte_in_low);
#endif
}

// ---- K1: fused CSR build: histogram + scan + fill in LDS, coalesced write-out.
__global__ void __launch_bounds__(1024, 1)
k_csr(const int* __restrict__ ei, float* __restrict__ dis,
      int* __restrict__ startA, int* __restrict__ cntA,
      int* __restrict__ csr, float* __restrict__ emb) {
    __shared__ int hist[500];      // histogram, then cursor
    __shared__ int ws[512];        // scan workspace
    __shared__ int csr_l[QCAP];
    int gq = blockIdx.x;
    int g = gq >> 2, q = gq & 3;
    int lo = q * 500, hi = lo + 500;
    int tid = threadIdx.x;
    if (tid < 500) hist[tid] = 0;
    if (q == 0 && tid < 64) emb[g * 64 + tid] = 0.f;
    __syncthreads();
    const int* srcp = ei + (size_t)g * 2 * Ee;
    const int* dstp = srcp + Ee;
    for (int i = tid; i < Ee / 4; i += 1024) {
        int4 d = reinterpret_cast<const int4*>(dstp)[i];
        if (d.x >= lo && d.x < hi) atomicAdd(&hist[d.x - lo], 1);
        if (d.y >= lo && d.y < hi) atomicAdd(&hist[d.y - lo], 1);
        if (d.z >= lo && d.z < hi) atomicAdd(&hist[d.z - lo], 1);
        if (d.w >= lo && d.w < hi) atomicAdd(&hist[d.w - lo], 1);
    }
    __syncthreads();
    if (tid < 512) ws[tid] = (tid < 500) ? hist[tid] : 0;
    __syncthreads();
    for (int off = 1; off < 512; off <<= 1) {
        int v = 0;
        if (tid < 512 && tid >= off) v = ws[tid - off];
        __syncthreads();
        if (tid < 512) ws[tid] += v;
        __syncthreads();
    }
    if (tid < 500) {
        int cnt = hist[tid];
        int ex = ws[tid] - cnt;                    // exclusive prefix
        int n = lo + tid;
        startA[(size_t)g * Nn + n] = gq * QCAP + ex;
        cntA[(size_t)g * Nn + n]   = cnt;
        dis[(size_t)g * Nn + n]    = rsqrtf((float)cnt + 1.0f);
        hist[tid] = ex;                            // reuse as cursor
    }
    __syncthreads();
    for (int i = tid; i < Ee / 4; i += 1024) {
        int4 d = reinterpret_cast<const int4*>(dstp)[i];
        int4 s = reinterpret_cast<const int4*>(srcp)[i];
        if (d.x >= lo && d.x < hi) { int p = atomicAdd(&hist[d.x - lo], 1); if (p < QCAP) csr_l[p] = s.x; }
        if (d.y >= lo && d.y < hi) { int p = atomicAdd(&hist[d.y - lo], 1); if (p < QCAP) csr_l[p] = s.y; }
        if (d.z >= lo && d.z < hi) { int p = atomicAdd(&hist[d.z - lo], 1); if (p < QCAP) csr_l[p] = s.z; }
        if (d.w >= lo && d.w < hi) { int p = atomicAdd(&hist[d.w - lo], 1); if (p < QCAP) csr_l[p] = s.w; }
    }
    __syncthreads();
    int total = ws[511];
    int* cg = csr + (size_t)gq * QCAP;
    for (int i = tid; i < total; i += 1024) cg[i] = csr_l[i];
}

// ---- K2: packed ELL build, one thread per slot (fully coalesced 4B stores).
// Entry uint = src_idx (low16) | bf16(weight) (high16).
// slot0 = self (w=dn*dn); slots 1..min(cnt,31) = edges (w=dis[s]*dn); rest pad w=0.
__global__ void k_ellp(const float* __restrict__ dis, const int* __restrict__ startA,
                       const int* __restrict__ cntA, const int* __restrict__ csr,
                       unsigned* __restrict__ ell, int* __restrict__ ncA) {
    int t = blockIdx.x * 256 + threadIdx.x;     // G*Nn*SLOT threads
    int slot = t & (SLOT - 1);
    int gn = t >> 5;
    int g = gn / Nn;
    int n = gn - g * Nn;
    float dn = dis[gn];
    int cnt = cntA[gn];
    int m = min(cnt, SLOT - 1);
    unsigned v;
    if (slot == 0) {
        v = (unsigned)n | ((unsigned)f2bf(dn * dn) << 16);
        ncA[gn] = (m + 1 + 3) >> 2;             // # of int4 chunks (4 entries each)
    }
    if (slot > 0) {
        if (slot <= m) {
            int s = csr[startA[gn] + slot - 1];
            v = (unsigned)s | ((unsigned)f2bf(dis[(size_t)g * Nn + s] * dn) << 16);
        } else {
            v = (unsigned)n;                    // weight bits 0x0000 -> w = 0.0f
        }
    }
    ell[t] = v;
}

// ---- K3: fused per-node pipeline: aggX = ELL-agg(x) -> h1 = relu(aggX@W1+b1)
//          -> t2 = h1@W2 stored as fp8.  32 nodes/block, XCD-pinned.
__global__ void __launch_bounds__(256)
k_mmf(const float* __restrict__ x, const unsigned* __restrict__ ell,
      const int* __restrict__ ncA, const int* __restrict__ startA,
      const int* __restrict__ cntA, const int* __restrict__ csr,
      const float* __restrict__ dis,
      const float* __restrict__ W1, const float* __restrict__ b1,
      const float* __restrict__ W2, unsigned char* __restrict__ t2f) {
    __shared__ float Ws1[512];
    __shared__ float bs[64];
    __shared__ float xs[256];          // aggX tile: 32 nodes x 8 features
    __shared__ float W2s[4096];
    __shared__ float h1s[32 * 65];
    int i = blockIdx.x;            // 0..7559; round-robin over 8 XCDs
    int xcd = i & 7;
    int j = i >> 3;                // 0..944
    int f15 = j / 63;              // 0..14
    int bx = j % 63;
    int g = xcd * 15 + f15;
    int tid = threadIdx.x;
    Ws1[tid]       = W1[tid];
    Ws1[tid + 256] = W1[tid + 256];
    if (tid < 64) bs[tid] = b1[tid];
#pragma unroll
    for (int k2 = 0; k2 < 16; ++k2) W2s[k2 * 256 + tid] = W2[k2 * 256 + tid];
    // phase 0: packed-ELL aggregation of raw x (8-dim) into xs
    {
        int r0 = tid >> 3, f = tid & 7;       // node-in-block, feature
        int n = bx * 32 + r0;
        float v = 0.f;
        if (n < Nn) {
            size_t gn = (size_t)g * Nn + n;
            const float* xb = x + (size_t)g * Nn * 8;
            const uint4* ep = reinterpret_cast<const uint4*>(ell + gn * SLOT);
            int nc = ncA[gn];
            float acc = 0.f, acc2 = 0.f;
            uint4 p = ep[0];
            for (int c = 0; c < nc; ++c) {
                uint4 pn = ep[(c + 1 < nc) ? c + 1 : c];
                acc  += xb[(size_t)(p.x & 0xffffu) * 8 + f] * __uint_as_float(p.x & 0xffff0000u);
                acc2 += xb[(size_t)(p.y & 0xffffu) * 8 + f] * __uint_as_float(p.y & 0xffff0000u);
                acc  += xb[(size_t)(p.z & 0xffffu) * 8 + f] * __uint_as_float(p.z & 0xffff0000u);
                acc2 += xb[(size_t)(p.w & 0xffffu) * 8 + f] * __uint_as_float(p.w & 0xffff0000u);
                p = pn;
            }
            int cnt = cntA[gn];
            if (cnt > SLOT - 1) {              // rare overflow (deg > 31)
                float dnl = dis[gn];
                int o0 = startA[gn];
                const float* dsg = dis + (size_t)g * Nn;
                for (int e = SLOT - 1; e < cnt; ++e) {
                    int s = csr[o0 + e];
                    acc += xb[(size_t)s * 8 + f] * (dsg[s] * dnl);
                }
            }
            v = acc + acc2;
        }
        xs[tid] = v;                           // tid == r0*8+f
    }
    __syncthreads();
    // phase 1: h1 = relu(aggX@W1 + b1) into LDS
    int f = tid & 63, rr = tid >> 6;
#pragma unroll
    for (int ii = 0; ii < 8; ++ii) {
        int r = rr + 4 * ii;
        float acc = bs[f];
#pragma unroll
        for (int k = 0; k < 8; ++k) acc += xs[r * 8 + k] * Ws1[k * 64 + f];
        h1s[r * 65 + f] = fmaxf(acc, 0.f);
    }
    __syncthreads();
    // phase 2: t2 = h1 @ W2 (fp8 out), each thread: 1 node x 8 features
    int r2 = tid >> 3, fg = tid & 7;
    int n = bx * 32 + r2;
    if (n < Nn) {
        float4 a0 = {0.f, 0.f, 0.f, 0.f}, a1 = {0.f, 0.f, 0.f, 0.f};
        const float4* W24 = reinterpret_cast<const float4*>(W2s);
#pragma unroll 8
        for (int k = 0; k < 64; ++k) {
            float xv = h1s[r2 * 65 + k];
            float4 w0 = W24[k * 16 + fg * 2];
            float4 w1 = W24[k * 16 + fg * 2 + 1];
            a0.x += xv * w0.x; a0.y += xv * w0.y; a0.z += xv * w0.z; a0.w += xv * w0.w;
            a1.x += xv * w1.x; a1.y += xv * w1.y; a1.z += xv * w1.z; a1.w += xv * w1.w;
        }
        int2 ov;
        ov.x = (int)fp8_pack4(a0.x, a0.y, a0.z, a0.w);
        ov.y = (int)fp8_pack4(a1.x, a1.y, a1.z, a1.w);
        *reinterpret_cast<int2*>(t2f + ((size_t)g * Nn + n) * 64 + fg * 8) = ov;
    }
}

// ---- K4: h2 = relu(ELL-agg(t2 fp8)+b2) fused with mean-pool (h2 never stored).
// XCD-pinned; node per wave; fp8 rows = 1 cache line; prefetch-pipelined ELL.
__global__ void k_agg64f(const unsigned char* __restrict__ t2f, const unsigned* __restrict__ ell,
                         const int* __restrict__ ncA, const int* __restrict__ startA,
                         const int* __restrict__ cntA, const int* __restrict__ csr,
                         const float* __restrict__ dis, const float* __restrict__ bias,
                         float* __restrict__ emb) {
    __shared__ float red[256];
    int i = blockIdx.x;            // 0..59999
    int xcd = i & 7;
    int chunk = i >> 3;            // 0..7499
    int ng = chunk % 500;
    int f15 = chunk / 500;         // 0..14
    int g = xcd * 15 + f15;
    int n = ng * 4 + (threadIdx.x >> 6);
    int f = threadIdx.x & 63;
    size_t gn = (size_t)g * Nn + n;
    const unsigned char* base = t2f + (size_t)g * Nn * 64;
    const uint4* ep = reinterpret_cast<const uint4*>(ell + gn * SLOT);
    int nc = ncA[gn];              // wave-uniform (one node per wave)
    float acc = 0.f, acc2 = 0.f;
    uint4 p = ep[0];
    for (int c = 0; c < nc; ++c) {
        uint4 pn = ep[(c + 1 < nc) ? c + 1 : c];    // prefetch next chunk
        unsigned b0 = base[(size_t)(p.x & 0xffffu) * 64 + f];
        unsigned b1 = base[(size_t)(p.y & 0xffffu) * 64 + f];
        unsigned b2 = base[(size_t)(p.z & 0xffffu) * 64 + f];
        unsigned b3 = base[(size_t)(p.w & 0xffffu) * 64 + f];
        acc  += fp8_dec(b0) * __uint_as_float(p.x & 0xffff0000u);
        acc2 += fp8_dec(b1) * __uint_as_float(p.y & 0xffff0000u);
        acc  += fp8_dec(b2) * __uint_as_float(p.z & 0xffff0000u);
        acc2 += fp8_dec(b3) * __uint_as_float(p.w & 0xffff0000u);
        p = pn;
    }
    int cnt = cntA[gn];
    if (cnt > SLOT - 1) {           // rare overflow; wave-uniform branch
        float dn = dis[gn];
        int o0 = startA[gn];
        const float* dsg = dis + (size_t)g * Nn;
        for (int e = SLOT - 1; e < cnt; ++e) {
            int s = csr[o0 + e];
            acc += fp8_dec(base[(size_t)s * 64 + f]) * (dsg[s] * dn);
        }
    }
    float val = fmaxf(acc + acc2 + bias[f], 0.f);
    red[threadIdx.x] = val;
    __syncthreads();
    if (threadIdx.x < 64) {
        float s = red[threadIdx.x] + red[64 + threadIdx.x] +
                  red[128 + threadIdx.x] + red[192 + threadIdx.x];
        atomicAdd(&emb[g * 64 + threadIdx.x], s * (1.0f / Nn));
    }
}

// ---- K5: gi[g][384] = emb[g] @ W_ih^T + b_ih (parallel over frames)
__global__ void k_gi(const float* __restrict__ emb, const float* __restrict__ W_ih,
                     const float* __restrict__ b_ih, float* __restrict__ gi) {
    __shared__ float xs[64];
    int g = blockIdx.x;          // g = b*Tt + t
    int j = threadIdx.x;         // 0..383
    if (j < 64) xs[j] = emb[g * 64 + j];
    __syncthreads();
    float a0 = 0.f, a1 = 0.f, a2 = 0.f, a3 = 0.f;
    const float* wr = W_ih + j * 64;
#pragma unroll
    for (int k = 0; k < 16; ++k) {
        a0 += wr[4 * k + 0] * xs[4 * k + 0];
        a1 += wr[4 * k + 1] * xs[4 * k + 1];
        a2 += wr[4 * k + 2] * xs[4 * k + 2];
        a3 += wr[4 * k + 3] * xs[4 * k + 3];
    }
    gi[(size_t)g * 384 + j] = b_ih[j] + ((a0 + a1) + (a2 + a3));
}

// ---- K6: sequential GRU over T, one block per batch, W_hh in regs + final FC
__global__ void __launch_bounds__(768, 1)
k_gru_seq(const float* __restrict__ gi, const float* __restrict__ W_hh,
          const float* __restrict__ b_hh, const float* __restrict__ fc_w,
          const float* __restrict__ fc_b, float* __restrict__ out) {
    __shared__ float h[Fg];
    __shared__ float part[768];
    int b = blockIdx.x;                  // batch
    int tid = threadIdx.x;               // 0..767
    int row = tid >> 1;                  // gate-row 0..383
    int half = tid & 1;                  // which 64-slice of k
    float w[64];
    const float* wr = W_hh + (size_t)row * Fg + half * 64;
#pragma unroll
    for (int i = 0; i < 64; ++i) w[i] = wr[i];
    if (tid < Fg) h[tid] = 0.f;
    __syncthreads();
    for (int t = 0; t < Tt; ++t) {
        const float* hh = &h[half * 64];
        float a0 = 0.f, a1 = 0.f, a2 = 0.f, a3 = 0.f;
#pragma unroll
        for (int i = 0; i < 16; ++i) {
            a0 += w[4 * i + 0] * hh[4 * i + 0];
            a1 += w[4 * i + 1] * hh[4 * i + 1];
            a2 += w[4 * i + 2] * hh[4 * i + 2];
            a3 += w[4 * i + 3] * hh[4 * i + 3];
        }
        part[tid] = (a0 + a1) + (a2 + a3);
        __syncthreads();
        if (tid < Fg) {
            int j = tid;
            const float* gib = gi + ((size_t)b * Tt + t) * 384;
            float hr = b_hh[j]       + part[2 * j]           + part[2 * j + 1];
            float hz = b_hh[128 + j] + part[2 * (128 + j)]   + part[2 * (128 + j) + 1];
            float hn = b_hh[256 + j] + part[2 * (256 + j)]   + part[2 * (256 + j) + 1];
            float r  = 1.f / (1.f + expf(-(gib[j] + hr)));
            float z  = 1.f / (1.f + expf(-(gib[128 + j] + hz)));
            float nn = tanhf(gib[256 + j] + r * hn);
            h[j] = (1.f - z) * nn + z * h[j];
        }
        __syncthreads();
    }
    if (tid < 2) {
        float acc = fc_b[tid];
        for (int k = 0; k < Fg; ++k) acc += fc_w[tid * Fg + k] * h[k];
        out[b * 2 + tid] = acc;
    }
}

// ----------------------------------------------------------------- launcher
extern "C" void kernel_launch(void* const* d_in, const int* in_sizes, int n_in,
                              void* d_out, int out_size, void* d_ws, size_t ws_size,
                              hipStream_t stream) {
    const float* x     = (const float*)d_in[0];
    const int*   ei    = (const int*)  d_in[1];
    const float* W1    = (const float*)d_in[2];
    const float* b1    = (const float*)d_in[3];
    const float* W2    = (const float*)d_in[4];
    const float* b2    = (const float*)d_in[5];
    const float* W_ih  = (const float*)d_in[6];
    const float* W_hh  = (const float*)d_in[7];
    const float* b_ih  = (const float*)d_in[8];
    const float* b_hh  = (const float*)d_in[9];
    const float* fc_w  = (const float*)d_in[10];
    const float* fc_b  = (const float*)d_in[11];
    float* out = (float*)d_out;

    char* ws = (char*)d_ws;
    size_t off = 0;
    auto alloc = [&](size_t bytes) -> void* {
        void* p = ws + off;
        off = (off + bytes + 255) & ~(size_t)255;
        return p;
    };
    float*    dis    = (float*)   alloc((size_t)G * Nn * 4);
    int*      startA = (int*)     alloc((size_t)G * Nn * 4);
    int*      cntA   = (int*)     alloc((size_t)G * Nn * 4);
    int*      ncA    = (int*)     alloc((size_t)G * Nn * 4);
    int*      csr    = (int*)     alloc((size_t)G * 4 * QCAP * 4);
    unsigned* ell    = (unsigned*)alloc((size_t)G * Nn * SLOT * 4);
    unsigned char* t2f = (unsigned char*)alloc((size_t)G * Nn * 64);
    float*    emb    = (float*)   alloc((size_t)G * 64 * 4);
    float*    gi     = (float*)   alloc((size_t)G * 384 * 4);
    (void)ws_size; (void)in_sizes; (void)n_in; (void)out_size;

    hipLaunchKernelGGL(k_csr,    dim3(G * 4), dim3(1024), 0, stream, ei, dis, startA, cntA, csr, emb);
    hipLaunchKernelGGL(k_ellp,   dim3(G * Nn * SLOT / 256), dim3(256), 0, stream, dis, startA, cntA, csr, ell, ncA);
    hipLaunchKernelGGL(k_mmf,    dim3(7560), dim3(256), 0, stream, x, ell, ncA, startA, cntA, csr, dis, W1, b1, W2, t2f);
    hipLaunchKernelGGL(k_agg64f, dim3(60000), dim3(256), 0, stream, t2f, ell, ncA, startA, cntA, csr, dis, b2, emb);
    hipLaunchKernelGGL(k_gi,     dim3(G), dim3(384), 0, stream, emb, W_ih, b_ih, gi);
    hipLaunchKernelGGL(k_gru_seq, dim3(Bb), dim3(768), 0, stream, gi, W_hh, b_hh, fc_w, fc_b, out);
}

// Round 10
// 329.269 us; speedup vs baseline: 1.7786x; 1.6440x over previous
//
#include <hip/hip_runtime.h>
#include <math.h>

// Problem constants (fixed by the reference)
#define G    120     // B*T frames
#define Nn   2000    // nodes per frame
#define Ee   32000   // edges per frame
#define Tt   30
#define Bb   4
#define Fg   128     // GRU hidden
#define QCAP 9216    // CSR capacity per (frame,quadrant); expected 8000, sigma 78
#define TSLOT 48     // transposed-ELL slots/node: slot0=self + up to 47 edges

static __device__ __forceinline__ unsigned short f2bf(float f) {
    unsigned u = __float_as_uint(f);
    u += 0x7fffu + ((u >> 16) & 1u);          // round-to-nearest-even
    return (unsigned short)(u >> 16);
}

// ---------------- fp8 e4m3 encode/decode: HW builtins if available, SW fallback.
#if defined(__has_builtin)
#if __has_builtin(__builtin_amdgcn_cvt_f32_fp8) && __has_builtin(__builtin_amdgcn_cvt_pk_fp8_f32)
#define HW_FP8 1
#endif
#if __has_builtin(__builtin_amdgcn_cvt_pk_f32_fp8)
#define HW_FP8_PK 1
typedef float floatx2 __attribute__((ext_vector_type(2)));
#endif
#endif

static __device__ __forceinline__ unsigned fp8_enc_sw(float x) {
    unsigned s = (__float_as_uint(x) >> 24) & 0x80u;
    float ax = fminf(fabsf(x), 448.f);
    unsigned em;
    if (ax < 0.015625f) {
        em = (unsigned)__float2int_rn(ax * 512.f);
    } else {
        int e = (int)(__float_as_uint(ax) >> 23) - 127;
        float r = ax * __uint_as_float((unsigned)((130 - e) << 23));
        int q = __float2int_rn(r);
        em = (unsigned)(((e + 7) << 3) + (q - 8));
        em = min(em, 126u);
    }
    return s | em;
}
static __device__ __forceinline__ float fp8_dec_sw(unsigned b) {
    unsigned em = b & 0x7fu;
    float mag;
    if (em < 8u) mag = (float)em * 0.001953125f;
    else mag = __uint_as_float((((em >> 3) + 120u) << 23) | ((em & 7u) << 20));
    return (b & 0x80u) ? -mag : mag;
}
static __device__ __forceinline__ unsigned fp8_pack4(float a, float b, float c, float d) {
#ifdef HW_FP8
    int w = __builtin_amdgcn_cvt_pk_fp8_f32(a, b, 0, false);
    w = __builtin_amdgcn_cvt_pk_fp8_f32(c, d, w, true);
    return (unsigned)w;
#else
    return fp8_enc_sw(a) | (fp8_enc_sw(b) << 8) | (fp8_enc_sw(c) << 16) | (fp8_enc_sw(d) << 24);
#endif
}
// decode 4 fp8 from one dword into o[0..3]
static __device__ __forceinline__ void fp8x4_dec(unsigned dw, float* o) {
#ifdef HW_FP8_PK
    floatx2 lo = __builtin_amdgcn_cvt_pk_f32_fp8((int)dw, false);
    floatx2 hi = __builtin_amdgcn_cvt_pk_f32_fp8((int)dw, true);
    o[0] = lo[0]; o[1] = lo[1]; o[2] = hi[0]; o[3] = hi[1];
#else
    o[0] = fp8_dec_sw(dw & 0xffu);
    o[1] = fp8_dec_sw((dw >> 8) & 0xffu);
    o[2] = fp8_dec_sw((dw >> 16) & 0xffu);
    o[3] = fp8_dec_sw((dw >> 24) & 0xffu);
#endif
}

// ---- K1: fused CSR build: histogram + scan + fill in LDS, coalesced write-out.
__global__ void __launch_bounds__(1024, 1)
k_csr(const int* __restrict__ ei, float* __restrict__ dis,
      int* __restrict__ startA, int* __restrict__ cntA,
      int* __restrict__ csr, float* __restrict__ emb) {
    __shared__ int hist[500];      // histogram, then cursor
    __shared__ int ws[512];        // scan workspace
    __shared__ int csr_l[QCAP];
    int gq = blockIdx.x;
    int g = gq >> 2, q = gq & 3;
    int lo = q * 500, hi = lo + 500;
    int tid = threadIdx.x;
    if (tid < 500) hist[tid] = 0;
    if (q == 0 && tid < 64) emb[g * 64 + tid] = 0.f;
    __syncthreads();
    const int* srcp = ei + (size_t)g * 2 * Ee;
    const int* dstp = srcp + Ee;
    for (int i = tid; i < Ee / 4; i += 1024) {
        int4 d = reinterpret_cast<const int4*>(dstp)[i];
        if (d.x >= lo && d.x < hi) atomicAdd(&hist[d.x - lo], 1);
        if (d.y >= lo && d.y < hi) atomicAdd(&hist[d.y - lo], 1);
        if (d.z >= lo && d.z < hi) atomicAdd(&hist[d.z - lo], 1);
        if (d.w >= lo && d.w < hi) atomicAdd(&hist[d.w - lo], 1);
    }
    __syncthreads();
    if (tid < 512) ws[tid] = (tid < 500) ? hist[tid] : 0;
    __syncthreads();
    for (int off = 1; off < 512; off <<= 1) {
        int v = 0;
        if (tid < 512 && tid >= off) v = ws[tid - off];
        __syncthreads();
        if (tid < 512) ws[tid] += v;
        __syncthreads();
    }
    if (tid < 500) {
        int cnt = hist[tid];
        int ex = ws[tid] - cnt;                    // exclusive prefix
        int n = lo + tid;
        startA[(size_t)g * Nn + n] = gq * QCAP + ex;
        cntA[(size_t)g * Nn + n]   = cnt;
        dis[(size_t)g * Nn + n]    = rsqrtf((float)cnt + 1.0f);
        hist[tid] = ex;                            // reuse as cursor
    }
    __syncthreads();
    for (int i = tid; i < Ee / 4; i += 1024) {
        int4 d = reinterpret_cast<const int4*>(dstp)[i];
        int4 s = reinterpret_cast<const int4*>(srcp)[i];
        if (d.x >= lo && d.x < hi) { int p = atomicAdd(&hist[d.x - lo], 1); if (p < QCAP) csr_l[p] = s.x; }
        if (d.y >= lo && d.y < hi) { int p = atomicAdd(&hist[d.y - lo], 1); if (p < QCAP) csr_l[p] = s.y; }
        if (d.z >= lo && d.z < hi) { int p = atomicAdd(&hist[d.z - lo], 1); if (p < QCAP) csr_l[p] = s.z; }
        if (d.w >= lo && d.w < hi) { int p = atomicAdd(&hist[d.w - lo], 1); if (p < QCAP) csr_l[p] = s.w; }
    }
    __syncthreads();
    int total = ws[511];
    int* cg = csr + (size_t)gq * QCAP;
    for (int i = tid; i < total; i += 1024) cg[i] = csr_l[i];
}

// ---- K2: build slot-major transposed ELL (entry = src | bf16(w)<<16) in LDS,
// trimmed coalesced write-out; then agg1 (8-dim x) node-per-lane using the LDS
// entries, writing aggX. Block = (frame, 128-node chunk). XCD-pinned.
__global__ void __launch_bounds__(128)
k_prep(const int* __restrict__ csr, const int* __restrict__ startA,
       const int* __restrict__ cntA, const float* __restrict__ dis,
       const float* __restrict__ x, unsigned* __restrict__ ellT,
       float* __restrict__ aggX) {
    __shared__ unsigned lbuf[TSLOT * 128];     // [slot][node-in-chunk], 24.6 KB
    __shared__ int cmaxS;
    int i = blockIdx.x;                 // 1920 = 8 xcd * 15 frames * 16 chunks
    int xcd = i & 7;
    int j = i >> 3;                     // 0..239
    int g = xcd * 15 + (j >> 4);
    int chunk = j & 15;                 // 0..15
    int tid = threadIdx.x;              // 0..127
    int n = chunk * 128 + tid;
    bool valid = (n < Nn);
    size_t gn = (size_t)g * Nn + n;
    if (tid == 0) cmaxS = 0;
    __syncthreads();
    int cnt = valid ? cntA[gn] : 0;
    int m = min(cnt, TSLOT - 1);
    int myc = valid ? (m + 1) : 0;
    float dn = valid ? dis[gn] : 0.f;
    const float* dsg = dis + (size_t)g * Nn;
    int start = valid ? startA[gn] : 0;
    if (valid) {
        lbuf[tid] = (unsigned)n | ((unsigned)f2bf(dn * dn) << 16);   // self-loop
        for (int e = 0; e < m; ++e) {
            int s = csr[start + e];
            lbuf[(e + 1) * 128 + tid] = (unsigned)s | ((unsigned)f2bf(dsg[s] * dn) << 16);
        }
    }
    atomicMax(&cmaxS, myc);
    __syncthreads();
    int cmax = cmaxS;
    // trimmed coalesced write-out
    if (valid) {
        unsigned* outp = ellT + (size_t)g * TSLOT * Nn + chunk * 128 + tid;
        for (int e = 0; e < cmax; ++e) outp[(size_t)e * Nn] = lbuf[e * 128 + tid];
    }
    // agg1: node-per-lane gather of x rows (32 B), entries from LDS
    const float4* x4 = reinterpret_cast<const float4*>(x + (size_t)g * Nn * 8);
    float4 aL = {0.f, 0.f, 0.f, 0.f}, aH = {0.f, 0.f, 0.f, 0.f};
    for (int e = 0; e < myc; ++e) {
        unsigned p = lbuf[e * 128 + tid];
        float w = __uint_as_float(p & 0xffff0000u);
        int s = p & 0xffffu;
        float4 r0 = x4[s * 2], r1 = x4[s * 2 + 1];
        aL.x += r0.x * w; aL.y += r0.y * w; aL.z += r0.z * w; aL.w += r0.w * w;
        aH.x += r1.x * w; aH.y += r1.y * w; aH.z += r1.z * w; aH.w += r1.w * w;
    }
    if (cnt > TSLOT - 1) {              // rare overflow (deg > 47)
        for (int e = TSLOT - 1; e < cnt; ++e) {
            int s = csr[start + e];
            float w = dsg[s] * dn;
            float4 r0 = x4[s * 2], r1 = x4[s * 2 + 1];
            aL.x += r0.x * w; aL.y += r0.y * w; aL.z += r0.z * w; aL.w += r0.w * w;
            aH.x += r1.x * w; aH.y += r1.y * w; aH.z += r1.z * w; aH.w += r1.w * w;
        }
    }
    if (valid) {
        float4* op = reinterpret_cast<float4*>(aggX + gn * 8);
        op[0] = aL; op[1] = aH;
    }
}

// ---- K3: MLP per node: h1 = relu(aggX@W1 + b1) -> t2 = h1@W2 stored fp8.
// 32 nodes/block, XCD-pinned (same g-mapping as producers/consumers).
__global__ void __launch_bounds__(256)
k_mmf(const float* __restrict__ aggX,
      const float* __restrict__ W1, const float* __restrict__ b1,
      const float* __restrict__ W2, unsigned char* __restrict__ t2f) {
    __shared__ float Ws1[512];
    __shared__ float bs[64];
    __shared__ float xs[256];          // aggX tile: 32 nodes x 8 features
    __shared__ float W2s[4096];
    __shared__ float h1s[32 * 65];
    int i = blockIdx.x;            // 0..7559; round-robin over 8 XCDs
    int xcd = i & 7;
    int j = i >> 3;                // 0..944
    int f15 = j / 63;              // 0..14
    int bx = j % 63;
    int g = xcd * 15 + f15;
    int tid = threadIdx.x;
    Ws1[tid]       = W1[tid];
    Ws1[tid + 256] = W1[tid + 256];
    if (tid < 64) bs[tid] = b1[tid];
#pragma unroll
    for (int k2 = 0; k2 < 16; ++k2) W2s[k2 * 256 + tid] = W2[k2 * 256 + tid];
    { int idx = bx * 256 + tid; xs[tid] = (idx < Nn * 8) ? aggX[(size_t)g * Nn * 8 + idx] : 0.f; }
    __syncthreads();
    // phase 1: h1 = relu(aggX@W1 + b1) into LDS
    int f = tid & 63, rr = tid >> 6;
#pragma unroll
    for (int ii = 0; ii < 8; ++ii) {
        int r = rr + 4 * ii;
        float acc = bs[f];
#pragma unroll
        for (int k = 0; k < 8; ++k) acc += xs[r * 8 + k] * Ws1[k * 64 + f];
        h1s[r * 65 + f] = fmaxf(acc, 0.f);
    }
    __syncthreads();
    // phase 2: t2 = h1 @ W2 (fp8 out), each thread: 1 node x 8 features
    int r2 = tid >> 3, fg = tid & 7;
    int n = bx * 32 + r2;
    if (n < Nn) {
        float4 a0 = {0.f, 0.f, 0.f, 0.f}, a1 = {0.f, 0.f, 0.f, 0.f};
        const float4* W24 = reinterpret_cast<const float4*>(W2s);
#pragma unroll 8
        for (int k = 0; k < 64; ++k) {
            float xv = h1s[r2 * 65 + k];
            float4 w0 = W24[k * 16 + fg * 2];
            float4 w1 = W24[k * 16 + fg * 2 + 1];
            a0.x += xv * w0.x; a0.y += xv * w0.y; a0.z += xv * w0.z; a0.w += xv * w0.w;
            a1.x += xv * w1.x; a1.y += xv * w1.y; a1.z += xv * w1.z; a1.w += xv * w1.w;
        }
        int2 ov;
        ov.x = (int)fp8_pack4(a0.x, a0.y, a0.z, a0.w);
        ov.y = (int)fp8_pack4(a1.x, a1.y, a1.z, a1.w);
        *reinterpret_cast<int2*>(t2f + ((size_t)g * Nn + n) * 64 + fg * 8) = ov;
    }
}

// ---- K4: node-per-lane aggregation of t2 (fp8) + relu + mean-pool.
// Wave = 64 dst nodes; acc[64] features in VGPRs; per slot: coalesced ELL_T
// read + per-lane 64B row (4x dwordx4, L1-line-resident) + 32 pk-cvt + 64 fma.
__global__ void __launch_bounds__(256)
k_agg64R(const unsigned char* __restrict__ t2f, const unsigned* __restrict__ ellT,
         const int* __restrict__ cntA, const int* __restrict__ startA,
         const int* __restrict__ csr, const float* __restrict__ dis,
         const float* __restrict__ bias, float* __restrict__ emb) {
    int i = blockIdx.x;                 // 960 = 8 xcd * 15 frames * 8 node-blocks
    int xcd = i & 7;
    int j = i >> 3;                     // 0..119
    int g = xcd * 15 + (j >> 3);
    int blk = j & 7;                    // 256-node block
    int tid = threadIdx.x;
    int lane = tid & 63;
    int n = blk * 256 + tid;            // waves cover consecutive 64-node groups
    bool valid = (n < Nn);
    size_t gn = (size_t)g * Nn + n;
    int cnt = valid ? cntA[gn] : 0;
    int myc = valid ? (min(cnt, TSLOT - 1) + 1) : 0;
    float acc[64];
#pragma unroll
    for (int k = 0; k < 64; ++k) acc[k] = 0.f;
    const unsigned* et = ellT + (size_t)g * TSLOT * Nn + n;
    const uint4* t2g = reinterpret_cast<const uint4*>(t2f + (size_t)g * Nn * 64);
#define ROWFMA(dw, base) { float o_[4]; fp8x4_dec(dw, o_); \
    acc[base + 0] += o_[0] * w; acc[base + 1] += o_[1] * w; \
    acc[base + 2] += o_[2] * w; acc[base + 3] += o_[3] * w; }
    for (int e = 0; e < TSLOT; ++e) {
        if (!__any(e < myc)) break;
        if (e < myc) {
            unsigned p = et[(size_t)e * Nn];
            float w = __uint_as_float(p & 0xffff0000u);
            int s = p & 0xffffu;
            const uint4* row = t2g + s * 4;
            uint4 r0 = row[0], r1 = row[1], r2 = row[2], r3 = row[3];
            ROWFMA(r0.x, 0)  ROWFMA(r0.y, 4)  ROWFMA(r0.z, 8)  ROWFMA(r0.w, 12)
            ROWFMA(r1.x, 16) ROWFMA(r1.y, 20) ROWFMA(r1.z, 24) ROWFMA(r1.w, 28)
            ROWFMA(r2.x, 32) ROWFMA(r2.y, 36) ROWFMA(r2.z, 40) ROWFMA(r2.w, 44)
            ROWFMA(r3.x, 48) ROWFMA(r3.y, 52) ROWFMA(r3.z, 56) ROWFMA(r3.w, 60)
        }
    }
    if (cnt > TSLOT - 1) {              // rare overflow (deg > 47)
        float dn = dis[gn];
        int start = startA[gn];
        const float* dsg = dis + (size_t)g * Nn;
        for (int e = TSLOT - 1; e < cnt; ++e) {
            int s = csr[start + e];
            float w = dsg[s] * dn;
            const uint4* row = t2g + s * 4;
            uint4 r0 = row[0], r1 = row[1], r2 = row[2], r3 = row[3];
            ROWFMA(r0.x, 0)  ROWFMA(r0.y, 4)  ROWFMA(r0.z, 8)  ROWFMA(r0.w, 12)
            ROWFMA(r1.x, 16) ROWFMA(r1.y, 20) ROWFMA(r1.z, 24) ROWFMA(r1.w, 28)
            ROWFMA(r2.x, 32) ROWFMA(r2.y, 36) ROWFMA(r2.z, 40) ROWFMA(r2.w, 44)
            ROWFMA(r3.x, 48) ROWFMA(r3.y, 52) ROWFMA(r3.z, 56) ROWFMA(r3.w, 60)
        }
    }
#undef ROWFMA
    // bias + relu + wave-pool (butterfly per feature), then 1 atomic per lane
    float mypool = 0.f;
#pragma unroll
    for (int k = 0; k < 64; ++k) {
        float v = valid ? fmaxf(acc[k] + bias[k], 0.f) : 0.f;
        v += __shfl_xor(v, 1);  v += __shfl_xor(v, 2);  v += __shfl_xor(v, 4);
        v += __shfl_xor(v, 8);  v += __shfl_xor(v, 16); v += __shfl_xor(v, 32);
        if (lane == k) mypool = v;
    }
    atomicAdd(&emb[g * 64 + lane], mypool * (1.0f / Nn));
}

// ---- K5: gi[g][384] = emb[g] @ W_ih^T + b_ih (parallel over frames)
__global__ void k_gi(const float* __restrict__ emb, const float* __restrict__ W_ih,
                     const float* __restrict__ b_ih, float* __restrict__ gi) {
    __shared__ float xs[64];
    int g = blockIdx.x;          // g = b*Tt + t
    int j = threadIdx.x;         // 0..383
    if (j < 64) xs[j] = emb[g * 64 + j];
    __syncthreads();
    float a0 = 0.f, a1 = 0.f, a2 = 0.f, a3 = 0.f;
    const float* wr = W_ih + j * 64;
#pragma unroll
    for (int k = 0; k < 16; ++k) {
        a0 += wr[4 * k + 0] * xs[4 * k + 0];
        a1 += wr[4 * k + 1] * xs[4 * k + 1];
        a2 += wr[4 * k + 2] * xs[4 * k + 2];
        a3 += wr[4 * k + 3] * xs[4 * k + 3];
    }
    gi[(size_t)g * 384 + j] = b_ih[j] + ((a0 + a1) + (a2 + a3));
}

// ---- K6: sequential GRU over T, one block per batch, W_hh in regs + final FC
__global__ void __launch_bounds__(768, 1)
k_gru_seq(const float* __restrict__ gi, const float* __restrict__ W_hh,
          const float* __restrict__ b_hh, const float* __restrict__ fc_w,
          const float* __restrict__ fc_b, float* __restrict__ out) {
    __shared__ float h[Fg];
    __shared__ float part[768];
    int b = blockIdx.x;                  // batch
    int tid = threadIdx.x;               // 0..767
    int row = tid >> 1;                  // gate-row 0..383
    int half = tid & 1;                  // which 64-slice of k
    float w[64];
    const float* wr = W_hh + (size_t)row * Fg + half * 64;
#pragma unroll
    for (int i = 0; i < 64; ++i) w[i] = wr[i];
    if (tid < Fg) h[tid] = 0.f;
    __syncthreads();
    for (int t = 0; t < Tt; ++t) {
        const float* hh = &h[half * 64];
        float a0 = 0.f, a1 = 0.f, a2 = 0.f, a3 = 0.f;
#pragma unroll
        for (int i = 0; i < 16; ++i) {
            a0 += w[4 * i + 0] * hh[4 * i + 0];
            a1 += w[4 * i + 1] * hh[4 * i + 1];
            a2 += w[4 * i + 2] * hh[4 * i + 2];
            a3 += w[4 * i + 3] * hh[4 * i + 3];
        }
        part[tid] = (a0 + a1) + (a2 + a3);
        __syncthreads();
        if (tid < Fg) {
            int j = tid;
            const float* gib = gi + ((size_t)b * Tt + t) * 384;
            float hr = b_hh[j]       + part[2 * j]           + part[2 * j + 1];
            float hz = b_hh[128 + j] + part[2 * (128 + j)]   + part[2 * (128 + j) + 1];
            float hn = b_hh[256 + j] + part[2 * (256 + j)]   + part[2 * (256 + j) + 1];
            float r  = 1.f / (1.f + expf(-(gib[j] + hr)));
            float z  = 1.f / (1.f + expf(-(gib[128 + j] + hz)));
            float nn = tanhf(gib[256 + j] + r * hn);
            h[j] = (1.f - z) * nn + z * h[j];
        }
        __syncthreads();
    }
    if (tid < 2) {
        float acc = fc_b[tid];
        for (int k = 0; k < Fg; ++k) acc += fc_w[tid * Fg + k] * h[k];
        out[b * 2 + tid] = acc;
    }
}

// ----------------------------------------------------------------- launcher
extern "C" void kernel_launch(void* const* d_in, const int* in_sizes, int n_in,
                              void* d_out, int out_size, void* d_ws, size_t ws_size,
                              hipStream_t stream) {
    const float* x     = (const float*)d_in[0];
    const int*   ei    = (const int*)  d_in[1];
    const float* W1    = (const float*)d_in[2];
    const float* b1    = (const float*)d_in[3];
    const float* W2    = (const float*)d_in[4];
    const float* b2    = (const float*)d_in[5];
    const float* W_ih  = (const float*)d_in[6];
    const float* W_hh  = (const float*)d_in[7];
    const float* b_ih  = (const float*)d_in[8];
    const float* b_hh  = (const float*)d_in[9];
    const float* fc_w  = (const float*)d_in[10];
    const float* fc_b  = (const float*)d_in[11];
    float* out = (float*)d_out;

    char* ws = (char*)d_ws;
    size_t off = 0;
    auto alloc = [&](size_t bytes) -> void* {
        void* p = ws + off;
        off = (off + bytes + 255) & ~(size_t)255;
        return p;
    };
    float*    dis    = (float*)   alloc((size_t)G * Nn * 4);
    int*      startA = (int*)     alloc((size_t)G * Nn * 4);
    int*      cntA   = (int*)     alloc((size_t)G * Nn * 4);
    int*      csr    = (int*)     alloc((size_t)G * 4 * QCAP * 4);
    unsigned* ellT   = (unsigned*)alloc((size_t)G * TSLOT * Nn * 4);
    float*    aggX   = (float*)   alloc((size_t)G * Nn * 8 * 4);
    unsigned char* t2f = (unsigned char*)alloc((size_t)G * Nn * 64);
    float*    emb    = (float*)   alloc((size_t)G * 64 * 4);
    float*    gi     = (float*)   alloc((size_t)G * 384 * 4);
    (void)ws_size; (void)in_sizes; (void)n_in; (void)out_size;

    hipLaunchKernelGGL(k_csr,    dim3(G * 4), dim3(1024), 0, stream, ei, dis, startA, cntA, csr, emb);
    hipLaunchKernelGGL(k_prep,   dim3(1920), dim3(128), 0, stream, csr, startA, cntA, dis, x, ellT, aggX);
    hipLaunchKernelGGL(k_mmf,    dim3(7560), dim3(256), 0, stream, aggX, W1, b1, W2, t2f);
    hipLaunchKernelGGL(k_agg64R, dim3(960), dim3(256), 0, stream, t2f, ellT, cntA, startA, csr, dis, b2, emb);
    hipLaunchKernelGGL(k_gi,     dim3(G), dim3(384), 0, stream, emb, W_ih, b_ih, gi);
    hipLaunchKernelGGL(k_gru_seq, dim3(Bb), dim3(768), 0, stream, gi, W_hh, b_hh, fc_w, fc_b, out);
}

// Round 12
// 292.179 us; speedup vs baseline: 2.0044x; 1.1269x over previous
//
#include <hip/hip_runtime.h>
#include <math.h>

// Problem constants (fixed by the reference)
#define G    120     // B*T frames
#define Nn   2000    // nodes per frame
#define Ee   32000   // edges per frame
#define Tt   30
#define Bb   4
#define Fg   128     // GRU hidden
#define QCAP 9216    // CSR capacity per (frame,quadrant); expected 8000, sigma 78
#define TSLOT 48     // transposed-ELL slots/node: slot0=self + up to 47 edges

static __device__ __forceinline__ unsigned short f2bf(float f) {
    unsigned u = __float_as_uint(f);
    u += 0x7fffu + ((u >> 16) & 1u);          // round-to-nearest-even
    return (unsigned short)(u >> 16);
}

// ---------------- fp8 e4m3 encode/decode: HW builtins if available, SW fallback.
#if defined(__has_builtin)
#if __has_builtin(__builtin_amdgcn_cvt_f32_fp8) && __has_builtin(__builtin_amdgcn_cvt_pk_fp8_f32)
#define HW_FP8 1
#endif
#if __has_builtin(__builtin_amdgcn_cvt_pk_f32_fp8)
#define HW_FP8_PK 1
typedef float floatx2 __attribute__((ext_vector_type(2)));
#endif
#endif

static __device__ __forceinline__ unsigned fp8_enc_sw(float x) {
    unsigned s = (__float_as_uint(x) >> 24) & 0x80u;
    float ax = fminf(fabsf(x), 448.f);
    unsigned em;
    if (ax < 0.015625f) {
        em = (unsigned)__float2int_rn(ax * 512.f);
    } else {
        int e = (int)(__float_as_uint(ax) >> 23) - 127;
        float r = ax * __uint_as_float((unsigned)((130 - e) << 23));
        int q = __float2int_rn(r);
        em = (unsigned)(((e + 7) << 3) + (q - 8));
        em = min(em, 126u);
    }
    return s | em;
}
static __device__ __forceinline__ float fp8_dec_sw(unsigned b) {
    unsigned em = b & 0x7fu;
    float mag;
    if (em < 8u) mag = (float)em * 0.001953125f;
    else mag = __uint_as_float((((em >> 3) + 120u) << 23) | ((em & 7u) << 20));
    return (b & 0x80u) ? -mag : mag;
}
static __device__ __forceinline__ unsigned fp8_pack4(float a, float b, float c, float d) {
#ifdef HW_FP8
    int w = __builtin_amdgcn_cvt_pk_fp8_f32(a, b, 0, false);
    w = __builtin_amdgcn_cvt_pk_fp8_f32(c, d, w, true);
    return (unsigned)w;
#else
    return fp8_enc_sw(a) | (fp8_enc_sw(b) << 8) | (fp8_enc_sw(c) << 16) | (fp8_enc_sw(d) << 24);
#endif
}
static __device__ __forceinline__ void fp8x4_dec(unsigned dw, float* o) {
#ifdef HW_FP8_PK
    floatx2 lo = __builtin_amdgcn_cvt_pk_f32_fp8((int)dw, false);
    floatx2 hi = __builtin_amdgcn_cvt_pk_f32_fp8((int)dw, true);
    o[0] = lo[0]; o[1] = lo[1]; o[2] = hi[0]; o[3] = hi[1];
#else
    o[0] = fp8_dec_sw(dw & 0xffu);
    o[1] = fp8_dec_sw((dw >> 8) & 0xffu);
    o[2] = fp8_dec_sw((dw >> 16) & 0xffu);
    o[3] = fp8_dec_sw((dw >> 24) & 0xffu);
#endif
}

// ---- K1: fused build: full-frame histogram + dis, own-quadrant CSR in LDS,
// then DIRECT emit of slot-major ellT (trimmed, coalesced) + aggX (8-dim x agg).
// Block = (frame g, dst-quadrant q of 500 nodes); all 4 q-blocks of a frame pin
// to the same XCD (ei slice + x slice L2-shared). Global csr written only on
// overflow (deg>47) for the exact fallback path.
__global__ void __launch_bounds__(1024, 1)
k_build(const int* __restrict__ ei, const float* __restrict__ x,
        float* __restrict__ dis, int* __restrict__ startA, int* __restrict__ cntA,
        int* __restrict__ csr, unsigned* __restrict__ ellT,
        float* __restrict__ aggX, float* __restrict__ emb) {
    __shared__ int   hist[Nn];        // counts, then own-quadrant cursor
    __shared__ float disl[Nn];
    __shared__ int   ws[512];
    __shared__ int   csr_l[QCAP];
    __shared__ int   ovfS;
    int i = blockIdx.x;               // 0..479
    int xcd = i & 7;
    int j = i >> 3;                   // 0..59
    int f15 = j >> 2;                 // 0..14
    int q = j & 3;
    int g = xcd * 15 + f15;
    int gq = g * 4 + q;
    int lo = q * 500;
    int tid = threadIdx.x;
    // P1: init
    for (int idx = tid; idx < Nn; idx += 1024) hist[idx] = 0;
    if (tid == 0) ovfS = 0;
    if (q == 0 && tid < 64) emb[g * 64 + tid] = 0.f;
    __syncthreads();
    // P2: full-frame histogram of destinations
    const int* srcp = ei + (size_t)g * 2 * Ee;
    const int* dstp = srcp + Ee;
    for (int it = tid; it < Ee / 4; it += 1024) {
        int4 d = reinterpret_cast<const int4*>(dstp)[it];
        atomicAdd(&hist[d.x], 1);
        atomicAdd(&hist[d.y], 1);
        atomicAdd(&hist[d.z], 1);
        atomicAdd(&hist[d.w], 1);
    }
    __syncthreads();
    // P3a: dis for all nodes; load own-quadrant counts for scan
    for (int idx = tid; idx < Nn; idx += 1024) disl[idx] = rsqrtf((float)hist[idx] + 1.0f);
    int cnt = 0;
    if (tid < 512) ws[tid] = (tid < 500) ? hist[lo + tid] : 0;
    if (tid < 500) cnt = hist[lo + tid];
    __syncthreads();
    // P3b: inclusive scan over 512
    for (int off = 1; off < 512; off <<= 1) {
        int v = 0;
        if (tid < 512 && tid >= off) v = ws[tid - off];
        __syncthreads();
        if (tid < 512) ws[tid] += v;
        __syncthreads();
    }
    int ex = 0;
    if (tid < 500) ex = ws[tid] - cnt;
    // P3c: cursor for own quadrant + overflow flag
    if (tid < 500) {
        hist[lo + tid] = ex;
        if (cnt > TSLOT - 1) atomicMax(&ovfS, 1);
    }
    __syncthreads();
    // P4: fill own-quadrant CSR in LDS
    for (int it = tid; it < Ee / 4; it += 1024) {
        int4 d = reinterpret_cast<const int4*>(dstp)[it];
        int4 s = reinterpret_cast<const int4*>(srcp)[it];
        if (d.x >= lo && d.x < lo + 500) { int p = atomicAdd(&hist[d.x], 1); if (p < QCAP) csr_l[p] = s.x; }
        if (d.y >= lo && d.y < lo + 500) { int p = atomicAdd(&hist[d.y], 1); if (p < QCAP) csr_l[p] = s.y; }
        if (d.z >= lo && d.z < lo + 500) { int p = atomicAdd(&hist[d.z], 1); if (p < QCAP) csr_l[p] = s.z; }
        if (d.w >= lo && d.w < lo + 500) { int p = atomicAdd(&hist[d.w], 1); if (p < QCAP) csr_l[p] = s.w; }
    }
    __syncthreads();
    // P5: emit per-node outputs (thread t owns node lo+t, t<500)
    if (tid < 500) {
        int n = lo + tid;
        size_t gn = (size_t)g * Nn + n;
        cntA[gn] = cnt;
        startA[gn] = gq * QCAP + ex;
        float dn = disl[n];
        dis[gn] = dn;
        int m = min(cnt, TSLOT - 1);
        const float4* x4 = reinterpret_cast<const float4*>(x + (size_t)g * Nn * 8);
        float4 aL = {0.f, 0.f, 0.f, 0.f}, aH = {0.f, 0.f, 0.f, 0.f};
        unsigned* et = ellT + (size_t)g * TSLOT * Nn + n;
        // slot 0: self-loop
        {
            unsigned u = (unsigned)n | ((unsigned)f2bf(dn * dn) << 16);
            et[0] = u;
            float w = __uint_as_float(u & 0xffff0000u);
            float4 r0 = x4[n * 2], r1 = x4[n * 2 + 1];
            aL.x += r0.x * w; aL.y += r0.y * w; aL.z += r0.z * w; aL.w += r0.w * w;
            aH.x += r1.x * w; aH.y += r1.y * w; aH.z += r1.z * w; aH.w += r1.w * w;
        }
        for (int e = 0; e < m; ++e) {
            int s = csr_l[ex + e];
            unsigned u = (unsigned)s | ((unsigned)f2bf(disl[s] * dn) << 16);
            et[(size_t)(e + 1) * Nn] = u;
            float w = __uint_as_float(u & 0xffff0000u);
            float4 r0 = x4[s * 2], r1 = x4[s * 2 + 1];
            aL.x += r0.x * w; aL.y += r0.y * w; aL.z += r0.z * w; aL.w += r0.w * w;
            aH.x += r1.x * w; aH.y += r1.y * w; aH.z += r1.z * w; aH.w += r1.w * w;
        }
        for (int e = TSLOT - 1; e < cnt; ++e) {       // rare overflow tail
            int s = csr_l[ex + e];
            float w = disl[s] * dn;
            float4 r0 = x4[s * 2], r1 = x4[s * 2 + 1];
            aL.x += r0.x * w; aL.y += r0.y * w; aL.z += r0.z * w; aL.w += r0.w * w;
            aH.x += r1.x * w; aH.y += r1.y * w; aH.z += r1.z * w; aH.w += r1.w * w;
        }
        float4* op = reinterpret_cast<float4*>(aggX + gn * 8);
        op[0] = aL; op[1] = aH;
    }
    __syncthreads();
    // P6: global CSR write only if some node overflowed (exact fallback path)
    if (ovfS) {
        int total = ws[511];
        int* cg = csr + (size_t)gq * QCAP;
        for (int it = tid; it < total; it += 1024) cg[it] = csr_l[it];
    }
}

// ---- K2: MLP per node: h1 = relu(aggX@W1 + b1) -> t2 = h1@W2 stored fp8.
// 32 nodes/block, XCD-pinned (same g-mapping as producers/consumers).
__global__ void __launch_bounds__(256)
k_mmf(const float* __restrict__ aggX,
      const float* __restrict__ W1, const float* __restrict__ b1,
      const float* __restrict__ W2, unsigned char* __restrict__ t2f) {
    __shared__ float Ws1[512];
    __shared__ float bs[64];
    __shared__ float xs[256];          // aggX tile: 32 nodes x 8 features
    __shared__ float W2s[4096];
    __shared__ float h1s[32 * 65];
    int i = blockIdx.x;            // 0..7559; round-robin over 8 XCDs
    int xcd = i & 7;
    int j = i >> 3;                // 0..944
    int f15 = j / 63;              // 0..14
    int bx = j % 63;
    int g = xcd * 15 + f15;
    int tid = threadIdx.x;
    Ws1[tid]       = W1[tid];
    Ws1[tid + 256] = W1[tid + 256];
    if (tid < 64) bs[tid] = b1[tid];
#pragma unroll
    for (int k2 = 0; k2 < 16; ++k2) W2s[k2 * 256 + tid] = W2[k2 * 256 + tid];
    { int idx = bx * 256 + tid; xs[tid] = (idx < Nn * 8) ? aggX[(size_t)g * Nn * 8 + idx] : 0.f; }
    __syncthreads();
    int f = tid & 63, rr = tid >> 6;
#pragma unroll
    for (int ii = 0; ii < 8; ++ii) {
        int r = rr + 4 * ii;
        float acc = bs[f];
#pragma unroll
        for (int k = 0; k < 8; ++k) acc += xs[r * 8 + k] * Ws1[k * 64 + f];
        h1s[r * 65 + f] = fmaxf(acc, 0.f);
    }
    __syncthreads();
    int r2 = tid >> 3, fg = tid & 7;
    int n = bx * 32 + r2;
    if (n < Nn) {
        float4 a0 = {0.f, 0.f, 0.f, 0.f}, a1 = {0.f, 0.f, 0.f, 0.f};
        const float4* W24 = reinterpret_cast<const float4*>(W2s);
#pragma unroll 8
        for (int k = 0; k < 64; ++k) {
            float xv = h1s[r2 * 65 + k];
            float4 w0 = W24[k * 16 + fg * 2];
            float4 w1 = W24[k * 16 + fg * 2 + 1];
            a0.x += xv * w0.x; a0.y += xv * w0.y; a0.z += xv * w0.z; a0.w += xv * w0.w;
            a1.x += xv * w1.x; a1.y += xv * w1.y; a1.z += xv * w1.z; a1.w += xv * w1.w;
        }
        int2 ov;
        ov.x = (int)fp8_pack4(a0.x, a0.y, a0.z, a0.w);
        ov.y = (int)fp8_pack4(a1.x, a1.y, a1.z, a1.w);
        *reinterpret_cast<int2*>(t2f + ((size_t)g * Nn + n) * 64 + fg * 8) = ov;
    }
}

// ---- K3: node-per-lane aggregation of t2 (fp8) + relu + mean-pool,
// feature-split: 512 thr = 8 waves; wave = 64 nodes x 32 features (acc[32]).
__global__ void __launch_bounds__(512)
k_agg64R2(const unsigned char* __restrict__ t2f, const unsigned* __restrict__ ellT,
          const int* __restrict__ cntA, const int* __restrict__ startA,
          const int* __restrict__ csr, const float* __restrict__ dis,
          const float* __restrict__ bias, float* __restrict__ emb) {
    int i = blockIdx.x;                 // 960 = 8 xcd * 15 frames * 8 node-blocks
    int xcd = i & 7;
    int j = i >> 3;                     // 0..119
    int g = xcd * 15 + (j >> 3);
    int blk = j & 7;                    // 256-node block
    int tid = threadIdx.x;              // 0..511
    int w = tid >> 6;                   // wave 0..7
    int lane = tid & 63;
    int ng = w >> 1;                    // node group 0..3
    int half = w & 1;                   // feature half
    int n = blk * 256 + ng * 64 + lane;
    bool valid = (n < Nn);
    size_t gn = (size_t)g * Nn + n;
    int cnt = valid ? cntA[gn] : 0;
    int myc = valid ? (min(cnt, TSLOT - 1) + 1) : 0;
    float acc[32];
#pragma unroll
    for (int k = 0; k < 32; ++k) acc[k] = 0.f;
    const unsigned* et = ellT + (size_t)g * TSLOT * Nn + n;
    const uint4* t2g = reinterpret_cast<const uint4*>(t2f + (size_t)g * Nn * 64);
#define ROWFMA(dw, base) { float o_[4]; fp8x4_dec(dw, o_); \
    acc[base + 0] += o_[0] * wt; acc[base + 1] += o_[1] * wt; \
    acc[base + 2] += o_[2] * wt; acc[base + 3] += o_[3] * wt; }
    for (int e = 0; e < TSLOT; ++e) {
        if (!__any(e < myc)) break;
        if (e < myc) {
            unsigned p = et[(size_t)e * Nn];
            float wt = __uint_as_float(p & 0xffff0000u);
            int s = p & 0xffffu;
            const uint4* row = t2g + s * 4 + half * 2;
            uint4 r0 = row[0], r1 = row[1];
            ROWFMA(r0.x, 0)  ROWFMA(r0.y, 4)  ROWFMA(r0.z, 8)  ROWFMA(r0.w, 12)
            ROWFMA(r1.x, 16) ROWFMA(r1.y, 20) ROWFMA(r1.z, 24) ROWFMA(r1.w, 28)
        }
    }
    if (cnt > TSLOT - 1) {              // rare overflow (deg > 47)
        float dn = dis[gn];
        int start = startA[gn];
        const float* dsg = dis + (size_t)g * Nn;
        for (int e = TSLOT - 1; e < cnt; ++e) {
            int s = csr[start + e];
            float wt = dsg[s] * dn;
            const uint4* row = t2g + s * 4 + half * 2;
            uint4 r0 = row[0], r1 = row[1];
            ROWFMA(r0.x, 0)  ROWFMA(r0.y, 4)  ROWFMA(r0.z, 8)  ROWFMA(r0.w, 12)
            ROWFMA(r1.x, 16) ROWFMA(r1.y, 20) ROWFMA(r1.z, 24) ROWFMA(r1.w, 28)
        }
    }
#undef ROWFMA
    // bias + relu + wave-pool (butterfly per feature), then 1 atomic per lane
    float mypool = 0.f;
#pragma unroll
    for (int k = 0; k < 32; ++k) {
        float v = valid ? fmaxf(acc[k] + bias[half * 32 + k], 0.f) : 0.f;
        v += __shfl_xor(v, 1);  v += __shfl_xor(v, 2);  v += __shfl_xor(v, 4);
        v += __shfl_xor(v, 8);  v += __shfl_xor(v, 16); v += __shfl_xor(v, 32);
        if (lane == k) mypool = v;
    }
    if (lane < 32) atomicAdd(&emb[g * 64 + half * 32 + lane], mypool * (1.0f / Nn));
}

// ---- K4: gi[g][384] = emb[g] @ W_ih^T + b_ih (parallel over frames)
__global__ void k_gi(const float* __restrict__ emb, const float* __restrict__ W_ih,
                     const float* __restrict__ b_ih, float* __restrict__ gi) {
    __shared__ float xs[64];
    int g = blockIdx.x;          // g = b*Tt + t
    int j = threadIdx.x;         // 0..383
    if (j < 64) xs[j] = emb[g * 64 + j];
    __syncthreads();
    float a0 = 0.f, a1 = 0.f, a2 = 0.f, a3 = 0.f;
    const float* wr = W_ih + j * 64;
#pragma unroll
    for (int k = 0; k < 16; ++k) {
        a0 += wr[4 * k + 0] * xs[4 * k + 0];
        a1 += wr[4 * k + 1] * xs[4 * k + 1];
        a2 += wr[4 * k + 2] * xs[4 * k + 2];
        a3 += wr[4 * k + 3] * xs[4 * k + 3];
    }
    gi[(size_t)g * 384 + j] = b_ih[j] + ((a0 + a1) + (a2 + a3));
}

// ---- K5: sequential GRU over T, one block per batch, W_hh in regs + final FC
__global__ void __launch_bounds__(768, 1)
k_gru_seq(const float* __restrict__ gi, const float* __restrict__ W_hh,
          const float* __restrict__ b_hh, const float* __restrict__ fc_w,
          const float* __restrict__ fc_b, float* __restrict__ out) {
    __shared__ float h[Fg];
    __shared__ float part[768];
    int b = blockIdx.x;                  // batch
    int tid = threadIdx.x;               // 0..767
    int row = tid >> 1;                  // gate-row 0..383
    int half = tid & 1;                  // which 64-slice of k
    float w[64];
    const float* wr = W_hh + (size_t)row * Fg + half * 64;
#pragma unroll
    for (int i = 0; i < 64; ++i) w[i] = wr[i];
    if (tid < Fg) h[tid] = 0.f;
    __syncthreads();
    for (int t = 0; t < Tt; ++t) {
        const float* hh = &h[half * 64];
        float a0 = 0.f, a1 = 0.f, a2 = 0.f, a3 = 0.f;
#pragma unroll
        for (int i = 0; i < 16; ++i) {
            a0 += w[4 * i + 0] * hh[4 * i + 0];
            a1 += w[4 * i + 1] * hh[4 * i + 1];
            a2 += w[4 * i + 2] * hh[4 * i + 2];
            a3 += w[4 * i + 3] * hh[4 * i + 3];
        }
        part[tid] = (a0 + a1) + (a2 + a3);
        __syncthreads();
        if (tid < Fg) {
            int j = tid;
            const float* gib = gi + ((size_t)b * Tt + t) * 384;
            float hr = b_hh[j]       + part[2 * j]           + part[2 * j + 1];
            float hz = b_hh[128 + j] + part[2 * (128 + j)]   + part[2 * (128 + j) + 1];
            float hn = b_hh[256 + j] + part[2 * (256 + j)]   + part[2 * (256 + j) + 1];
            float r  = 1.f / (1.f + expf(-(gib[j] + hr)));
            float z  = 1.f / (1.f + expf(-(gib[128 + j] + hz)));
            float nn = tanhf(gib[256 + j] + r * hn);
            h[j] = (1.f - z) * nn + z * h[j];
        }
        __syncthreads();
    }
    if (tid < 2) {
        float acc = fc_b[tid];
        for (int k = 0; k < Fg; ++k) acc += fc_w[tid * Fg + k] * h[k];
        out[b * 2 + tid] = acc;
    }
}

// ----------------------------------------------------------------- launcher
extern "C" void kernel_launch(void* const* d_in, const int* in_sizes, int n_in,
                              void* d_out, int out_size, void* d_ws, size_t ws_size,
                              hipStream_t stream) {
    const float* x     = (const float*)d_in[0];
    const int*   ei    = (const int*)  d_in[1];
    const float* W1    = (const float*)d_in[2];
    const float* b1    = (const float*)d_in[3];
    const float* W2    = (const float*)d_in[4];
    const float* b2    = (const float*)d_in[5];
    const float* W_ih  = (const float*)d_in[6];
    const float* W_hh  = (const float*)d_in[7];
    const float* b_ih  = (const float*)d_in[8];
    const float* b_hh  = (const float*)d_in[9];
    const float* fc_w  = (const float*)d_in[10];
    const float* fc_b  = (const float*)d_in[11];
    float* out = (float*)d_out;

    char* ws = (char*)d_ws;
    size_t off = 0;
    auto alloc = [&](size_t bytes) -> void* {
        void* p = ws + off;
        off = (off + bytes + 255) & ~(size_t)255;
        return p;
    };
    float*    dis    = (float*)   alloc((size_t)G * Nn * 4);
    int*      startA = (int*)     alloc((size_t)G * Nn * 4);
    int*      cntA   = (int*)     alloc((size_t)G * Nn * 4);
    int*      csr    = (int*)     alloc((size_t)G * 4 * QCAP * 4);
    unsigned* ellT   = (unsigned*)alloc((size_t)G * TSLOT * Nn * 4);
    float*    aggX   = (float*)   alloc((size_t)G * Nn * 8 * 4);
    unsigned char* t2f = (unsigned char*)alloc((size_t)G * Nn * 64);
    float*    emb    = (float*)   alloc((size_t)G * 64 * 4);
    float*    gi     = (float*)   alloc((size_t)G * 384 * 4);
    (void)ws_size; (void)in_sizes; (void)n_in; (void)out_size;

    hipLaunchKernelGGL(k_build,   dim3(480), dim3(1024), 0, stream, ei, x, dis, startA, cntA, csr, ellT, aggX, emb);
    hipLaunchKernelGGL(k_mmf,     dim3(7560), dim3(256), 0, stream, aggX, W1, b1, W2, t2f);
    hipLaunchKernelGGL(k_agg64R2, dim3(960), dim3(512), 0, stream, t2f, ellT, cntA, startA, csr, dis, b2, emb);
    hipLaunchKernelGGL(k_gi,      dim3(G), dim3(384), 0, stream, emb, W_ih, b_ih, gi);
    hipLaunchKernelGGL(k_gru_seq, dim3(Bb), dim3(768), 0, stream, gi, W_hh, b_hh, fc_w, fc_b, out);
}